// Round 1
// baseline (541.864 us; speedup 1.0000x reference)
//
#include <hip/hip_runtime.h>
#include <hip/hip_bf16.h>

// LINK forward: out[i, o] = b[o] + sum over edges (i -> j) of W[o, j]
// N=100000 nodes, OUT=64 channels, E=3200000 edges.
// Strategy: transpose W to W_T[N][64]; build CSR (count/scan/scatter of cols
// by row); gather with one wave per node (lane = channel, no output atomics).

#define OUTC 64
#define SCAN_ELEMS 1024   // elements per scan1 block (256 thr * 4 items)

// ---------------- transpose W[64][N] -> WT[N][64] ----------------
__global__ __launch_bounds__(256) void transpose_W(const float* __restrict__ W,
                                                   float* __restrict__ WT, int n) {
    __shared__ float tile[64][65];   // +1 pad
    const int n0   = blockIdx.x * 64;
    const int lane = threadIdx.x & 63;
    const int w    = threadIdx.x >> 6;   // 0..3
    // load: 64 rows (o), 64 cols (n); coalesced reads along n
    #pragma unroll
    for (int k = 0; k < 16; ++k) {
        int o = w * 16 + k;
        int nn = n0 + lane;
        tile[o][lane] = (nn < n) ? W[(size_t)o * n + nn] : 0.f;
    }
    __syncthreads();
    // store: coalesced along o
    #pragma unroll
    for (int k = 0; k < 16; ++k) {
        int nl = w * 16 + k;
        int nn = n0 + nl;
        if (nn < n) WT[(size_t)nn * OUTC + lane] = tile[lane][nl];
    }
}

// ---------------- histogram rows ----------------
__global__ __launch_bounds__(256) void count_rows(const int* __restrict__ rows,
                                                  int* __restrict__ counts, int E) {
    int e = blockIdx.x * blockDim.x + threadIdx.x;
    if (e < E) atomicAdd(&counts[rows[e]], 1);
}

// ---------------- 3-kernel exclusive scan over counts[0..n) ----------------
__global__ __launch_bounds__(256) void scan1(const int* __restrict__ counts,
                                             int* __restrict__ offsets,
                                             int* __restrict__ blockSums, int n) {
    __shared__ int lds[256];
    const int tid  = threadIdx.x;
    const int base = blockIdx.x * SCAN_ELEMS + tid * 4;
    int v[4];
    int s = 0;
    #pragma unroll
    for (int k = 0; k < 4; ++k) {
        v[k] = (base + k < n) ? counts[base + k] : 0;
        s += v[k];
    }
    lds[tid] = s;
    __syncthreads();
    // Hillis-Steele inclusive scan of per-thread sums
    for (int off = 1; off < 256; off <<= 1) {
        int t = 0;
        if (tid >= off) t = lds[tid - off];
        __syncthreads();
        if (tid >= off) lds[tid] += t;
        __syncthreads();
    }
    int ex = lds[tid] - s;   // exclusive prefix for this thread
    #pragma unroll
    for (int k = 0; k < 4; ++k) {
        if (base + k < n) offsets[base + k] = ex;
        ex += v[k];
    }
    if (tid == 255) blockSums[blockIdx.x] = lds[255];
}

__global__ __launch_bounds__(256) void scan2(int* __restrict__ blockSums, int nb) {
    __shared__ int lds[256];
    const int tid = threadIdx.x;
    int v = (tid < nb) ? blockSums[tid] : 0;
    lds[tid] = v;
    __syncthreads();
    for (int off = 1; off < 256; off <<= 1) {
        int t = 0;
        if (tid >= off) t = lds[tid - off];
        __syncthreads();
        if (tid >= off) lds[tid] += t;
        __syncthreads();
    }
    if (tid < nb) blockSums[tid] = lds[tid] - v;   // exclusive
}

__global__ __launch_bounds__(256) void scan3(int* __restrict__ offsets,
                                             const int* __restrict__ blockSums,
                                             int n, int E) {
    int i = blockIdx.x * blockDim.x + threadIdx.x;
    if (i < n) offsets[i] += blockSums[i >> 10];   // SCAN_ELEMS == 1024
    if (i == 0) offsets[n] = E;
}

// ---------------- scatter cols into CSR order ----------------
__global__ __launch_bounds__(256) void scatter_cols(const int* __restrict__ rows,
                                                    const int* __restrict__ cols,
                                                    const int* __restrict__ offsets,
                                                    int* __restrict__ cursor,
                                                    int* __restrict__ sorted_col, int E) {
    int e = blockIdx.x * blockDim.x + threadIdx.x;
    if (e < E) {
        int r = rows[e];
        int pos = atomicAdd(&cursor[r], 1);
        sorted_col[offsets[r] + pos] = cols[e];
    }
}

// ---------------- gather: one wave per node, lane = channel ----------------
__global__ __launch_bounds__(256) void gather_node(const float* __restrict__ WT,
                                                   const int* __restrict__ sorted_col,
                                                   const int* __restrict__ offsets,
                                                   const float* __restrict__ bias,
                                                   float* __restrict__ out, int n) {
    const int wave = (blockIdx.x * blockDim.x + threadIdx.x) >> 6;
    const int lane = threadIdx.x & 63;
    if (wave >= n) return;
    const int start = offsets[wave];
    const int end   = offsets[wave + 1];
    float a0 = bias[lane], a1 = 0.f, a2 = 0.f, a3 = 0.f;
    int e = start;
    for (; e + 3 < end; e += 4) {
        int c0 = sorted_col[e + 0];
        int c1 = sorted_col[e + 1];
        int c2 = sorted_col[e + 2];
        int c3 = sorted_col[e + 3];
        a0 += WT[(size_t)c0 * OUTC + lane];
        a1 += WT[(size_t)c1 * OUTC + lane];
        a2 += WT[(size_t)c2 * OUTC + lane];
        a3 += WT[(size_t)c3 * OUTC + lane];
    }
    for (; e < end; ++e) a0 += WT[(size_t)sorted_col[e] * OUTC + lane];
    out[(size_t)wave * OUTC + lane] = (a0 + a1) + (a2 + a3);
}

extern "C" void kernel_launch(void* const* d_in, const int* in_sizes, int n_in,
                              void* d_out, int out_size, void* d_ws, size_t ws_size,
                              hipStream_t stream) {
    const int*   edges = (const int*)d_in[0];    // [2, E]: rows then cols
    const float* W     = (const float*)d_in[1];  // [64, N]
    const float* bias  = (const float*)d_in[2];  // [64]
    float*       out   = (float*)d_out;          // [N, 64]

    const int E = in_sizes[0] / 2;
    const int N = in_sizes[1] / OUTC;

    // workspace layout
    char* ws = (char*)d_ws;
    size_t off = 0;
    float* WT = (float*)(ws + off);        off += (size_t)N * OUTC * sizeof(float);
    off = (off + 255) & ~(size_t)255;
    int* offsets = (int*)(ws + off);       off += (size_t)(N + 1) * sizeof(int);
    off = (off + 255) & ~(size_t)255;
    int* counts = (int*)(ws + off);        off += (size_t)N * sizeof(int);
    int* cursor = (int*)(ws + off);        off += (size_t)N * sizeof(int);   // contiguous with counts
    off = (off + 255) & ~(size_t)255;
    int* blockSums = (int*)(ws + off);     off += 256 * sizeof(int);
    off = (off + 255) & ~(size_t)255;
    int* sorted_col = (int*)(ws + off);    off += (size_t)E * sizeof(int);
    (void)ws_size;

    const int* rows = edges;
    const int* cols = edges + E;

    // zero counts + cursor (contiguous) in one memset
    hipMemsetAsync(counts, 0, (size_t)2 * N * sizeof(int), stream);

    transpose_W<<<(N + 63) / 64, 256, 0, stream>>>(W, WT, N);
    count_rows<<<(E + 255) / 256, 256, 0, stream>>>(rows, counts, E);

    const int nb1 = (N + SCAN_ELEMS - 1) / SCAN_ELEMS;   // 98 for N=100000
    scan1<<<nb1, 256, 0, stream>>>(counts, offsets, blockSums, N);
    scan2<<<1, 256, 0, stream>>>(blockSums, nb1);
    scan3<<<(N + 255) / 256, 256, 0, stream>>>(offsets, blockSums, N, E);

    scatter_cols<<<(E + 255) / 256, 256, 0, stream>>>(rows, cols, offsets, cursor,
                                                      sorted_col, E);

    // one wave per node: N waves, 4 waves/block
    gather_node<<<(N + 3) / 4, 256, 0, stream>>>(WT, sorted_col, offsets, bias, out, N);
}